// Round 2
// baseline (1043.410 us; speedup 1.0000x reference)
//
#include <hip/hip_runtime.h>

// Problem: B=8, N=4096, D=256, K=4096; T = B*N = 32768 tokens.
// Reference (numpy fp32 semantics, which the checker recomputes):
//   dist = -((x_sq - 2*(x@E^T)) + e_sq)   [each op rounded fp32, x_sq ~ 256]
//   idx = argmax(dist) = argmin over k of t2 = fl(fl(x_sq - 2*dot_k) + e_sq_k),
//         first occurrence (lowest k) on exact fp32 ties.
// The coarse grid (ulp ~1.5-3e-5 at magnitude 256) creates real ties; we must
// replicate the rounding pipeline, including numpy's pairwise-sum order for
// x_sq / e_sq, to match tie structure.

#define DDIM 256
#define BM 64     // tokens per block
#define BN 128    // codes per k-tile
#define BK 32     // D chunk
#define TM 4      // tokens per thread
#define TN 8      // codes per thread
// threads = (BM/TM) * (BN/TN) = 16 * 16 = 256

// ---- kernel 1: row sum-of-squares replicating numpy pairwise_sum(n=256) ----
// numpy: n=256 -> pw(0:128) + pw(128:256); each 128-block: 8 strided
// accumulators r_j (sequential adds, ascending), combine
// ((r0+r1)+(r2+r3))+((r4+r5)+(r6+r7)). Products rounded fp32 BEFORE adds.
__global__ __launch_bounds__(256) void sumsq_np_kernel(const float* __restrict__ in,
                                                       float* __restrict__ out) {
    const int tid = threadIdx.x;
    const int row = blockIdx.x * 16 + (tid >> 4);
    const int lane16 = tid & 15;
    const int j = lane16 & 7;
    const int half = lane16 >> 3;
    const float* p = in + (size_t)row * DDIM + half * 128 + j;

    float v0 = p[0];
    float pr = v0 * v0;
    asm volatile("" : "+v"(pr));      // forbid FMA contraction: round product
    float s = pr;
    #pragma unroll
    for (int k = 1; k < 16; k++) {
        float v = p[8 * k];
        float q = v * v;
        asm volatile("" : "+v"(q));   // round product separately
        s += q;                       // sequential adds, ascending k (numpy order)
    }
    // combine tree == numpy's: xor-shuffles within the 16-lane group
    s += __shfl_xor(s, 1);   // r0+r1 | r2+r3 | ...
    s += __shfl_xor(s, 2);   // (r0+r1)+(r2+r3) | ...
    s += __shfl_xor(s, 4);   // T_half at lanes 0 and 8
    s += __shfl_xor(s, 8);   // T1 + T2
    if (lane16 == 0) out[row] = s;
}

// ---- kernel 2: tiled fp32 matmul + running argmin of t2 (ref argmax) ----
__global__ __launch_bounds__(256) void argmax_kernel(const float* __restrict__ x,
                                                     const float* __restrict__ embed,
                                                     const float* __restrict__ xsq,
                                                     const float* __restrict__ esq,
                                                     int* __restrict__ out_idx,
                                                     int K) {
    __shared__ float xs[BK][BM + 1];   // transposed: xs[d][m]
    __shared__ float es[BK][BN + 4];   // transposed: es[d][n]

    const int tid = threadIdx.x;
    const int c = tid & 15;    // code-group 0..15 (TN=8 codes each)
    const int r = tid >> 4;    // token-group 0..15 (TM=4 tokens each)
    const int tm0 = blockIdx.x * BM;

    float xq[TM];
    #pragma unroll
    for (int i = 0; i < TM; i++) xq[i] = xsq[tm0 + r * TM + i];

    float best_val[TM];
    int   best_idx[TM];
    #pragma unroll
    for (int i = 0; i < TM; i++) { best_val[i] = INFINITY; best_idx[i] = 0; }

    for (int kt = 0; kt < K; kt += BN) {
        float acc[TM][TN];
        #pragma unroll
        for (int i = 0; i < TM; i++)
            #pragma unroll
            for (int j = 0; j < TN; j++) acc[i][j] = 0.0f;

        for (int d0 = 0; d0 < DDIM; d0 += BK) {
            __syncthreads();   // protect previous chunk's reads
            {   // stage x tile: BM x BK = 2048 floats
                int l = tid;
                #pragma unroll
                for (int it = 0; it < 2; it++, l += 256) {
                    const int row = l >> 3;
                    const int col = (l & 7) * 4;
                    float4 v = *reinterpret_cast<const float4*>(
                        x + (size_t)(tm0 + row) * DDIM + d0 + col);
                    xs[col + 0][row] = v.x; xs[col + 1][row] = v.y;
                    xs[col + 2][row] = v.z; xs[col + 3][row] = v.w;
                }
            }
            {   // stage e tile: BN x BK = 4096 floats
                int l = tid;
                #pragma unroll
                for (int it = 0; it < 4; it++, l += 256) {
                    const int row = l >> 3;
                    const int col = (l & 7) * 4;
                    float4 v = *reinterpret_cast<const float4*>(
                        embed + (size_t)(kt + row) * DDIM + d0 + col);
                    es[col + 0][row] = v.x; es[col + 1][row] = v.y;
                    es[col + 2][row] = v.z; es[col + 3][row] = v.w;
                }
            }
            __syncthreads();

            #pragma unroll
            for (int kk = 0; kk < BK; kk++) {
                float a[TM], b[TN];
                #pragma unroll
                for (int i = 0; i < TM; i++) a[i] = xs[kk][r * TM + i];
                #pragma unroll
                for (int j = 0; j < TN; j++) b[j] = es[kk][c * TN + j];
                #pragma unroll
                for (int i = 0; i < TM; i++)
                    #pragma unroll
                    for (int j = 0; j < TN; j++)
                        acc[i][j] = fmaf(a[i], b[j], acc[i][j]);
            }
        }

        // epilogue: t2 = fl(fl(x_sq - 2*dot) + e_sq); running argmin, ties->lowest k
        #pragma unroll
        for (int j = 0; j < TN; j++) {
            const int code = kt + c * TN + j;
            const float eq = esq[code];
            #pragma unroll
            for (int i = 0; i < TM; i++) {
                const float t1 = xq[i] - 2.0f * acc[i][j]; // 2*acc exact; one rounding
                const float t2 = t1 + eq;                  // one rounding
                if (t2 < best_val[i]) { best_val[i] = t2; best_idx[i] = code; }
            }
        }
    }

    // reduce across the 16 code-groups (same wave); min val, tie -> lower index
    #pragma unroll
    for (int i = 0; i < TM; i++) {
        float v = best_val[i];
        int   ix = best_idx[i];
        #pragma unroll
        for (int off = 1; off < 16; off <<= 1) {
            const float ov = __shfl_xor(v, off);
            const int   oi = __shfl_xor(ix, off);
            if (ov < v || (ov == v && oi < ix)) { v = ov; ix = oi; }
        }
        if (c == 0) out_idx[tm0 + r * TM + i] = ix;
    }
}

// ---- kernel 3: gather quantize = embed[idx], write indices as float ----
__global__ __launch_bounds__(256) void gather_kernel(const float* __restrict__ embed,
                                                     const int* __restrict__ idx,
                                                     float* __restrict__ quant,
                                                     float* __restrict__ out_ind) {
    const int wave = threadIdx.x >> 6;
    const int lane = threadIdx.x & 63;
    const int t = blockIdx.x * 4 + wave;
    const int k = idx[t];
    float4 v = reinterpret_cast<const float4*>(embed + (size_t)k * DDIM)[lane];
    reinterpret_cast<float4*>(quant + (size_t)t * DDIM)[lane] = v;
    if (lane == 0) out_ind[t] = (float)k;
}

extern "C" void kernel_launch(void* const* d_in, const int* in_sizes, int n_in,
                              void* d_out, int out_size, void* d_ws, size_t ws_size,
                              hipStream_t stream) {
    const float* x     = (const float*)d_in[0];
    const float* embed = (const float*)d_in[1];
    // d_in[2] = node_mask: does not affect the two outputs.

    const int T = in_sizes[0] / DDIM;   // 32768
    const int K = in_sizes[1] / DDIM;   // 4096

    float* xsq = (float*)d_ws;                       // T floats
    float* esq = xsq + T;                            // K floats
    int*   idx = (int*)(esq + K);                    // T ints

    float* quant   = (float*)d_out;
    float* out_ind = (float*)d_out + (size_t)T * DDIM;

    sumsq_np_kernel<<<T / 16, 256, 0, stream>>>(x, xsq);
    sumsq_np_kernel<<<K / 16, 256, 0, stream>>>(embed, esq);
    argmax_kernel<<<T / BM, 256, 0, stream>>>(x, embed, xsq, esq, idx, K);
    gather_kernel<<<T / 4, 256, 0, stream>>>(embed, idx, quant, out_ind);
}